// Round 1
// baseline (494.654 us; speedup 1.0000x reference)
//
#include <hip/hip_runtime.h>
#include <cstdint>

// Problem constants (fixed shapes for this dataset)
#define LSEQ 96
#define DCH  64
#define WID  256
#define NH   24
#define P5   120    // NH*5
#define HD   1536   // NH*DCH
#define NSUB 12     // poisson subkey ladder depth; P(need > 12) ~ 1e-13

// ---------------- Threefry-2x32 (20 rounds), matches jax._src.prng ----------------
__device__ __forceinline__ uint32_t rotl32(uint32_t x, int r) {
  return (x << r) | (x >> (32 - r));
}

__device__ __forceinline__ void tf2x32(uint32_t k0, uint32_t k1,
                                       uint32_t& x0, uint32_t& x1) {
  uint32_t k2 = k0 ^ k1 ^ 0x1BD11BDAu;
  x0 += k0; x1 += k1;
#define TF_R(r) { x0 += x1; x1 = rotl32(x1, r); x1 ^= x0; }
  TF_R(13) TF_R(15) TF_R(26) TF_R(6)
  x0 += k1; x1 += k2 + 1u;
  TF_R(17) TF_R(29) TF_R(16) TF_R(24)
  x0 += k2; x1 += k0 + 2u;
  TF_R(13) TF_R(15) TF_R(26) TF_R(6)
  x0 += k0; x1 += k1 + 3u;
  TF_R(17) TF_R(29) TF_R(16) TF_R(24)
  x0 += k1; x1 += k2 + 4u;
  TF_R(13) TF_R(15) TF_R(26) TF_R(6)
  x0 += k2; x1 += k0 + 5u;
#undef TF_R
}

// partitionable 32-bit random bits at 64-bit counter (c0=hi, c1=lo): bits1 ^ bits2
__device__ __forceinline__ uint32_t tf_bits32(uint32_t k0, uint32_t k1,
                                              uint32_t c0, uint32_t c1) {
  tf2x32(k0, k1, c0, c1);
  return c0 ^ c1;
}

// ---------------- uniform / normal exactly as jax.random ----------------
__device__ __forceinline__ float u01_from_bits(uint32_t b) {
  return __uint_as_float((b >> 9) | 0x3f800000u) - 1.0f;  // [0,1)
}

// XLA ErfInv f32 (Giles 2010), as in xla/client/lib/math.cc
__device__ __forceinline__ float erfinv_xla(float x) {
  float w = -log1pf(-x * x);
  float p;
  if (w < 5.0f) {
    w = w - 2.5f;
    p = 2.81022636e-08f;
    p = fmaf(p, w, 3.43273939e-07f);
    p = fmaf(p, w, -3.5233877e-06f);
    p = fmaf(p, w, -4.39150654e-06f);
    p = fmaf(p, w, 0.00021858087f);
    p = fmaf(p, w, -0.00125372503f);
    p = fmaf(p, w, -0.00417768164f);
    p = fmaf(p, w, 0.246640727f);
    p = fmaf(p, w, 1.50140941f);
  } else {
    w = sqrtf(w) - 3.0f;
    p = -0.000200214257f;
    p = fmaf(p, w, 0.000100950558f);
    p = fmaf(p, w, 0.00134934322f);
    p = fmaf(p, w, -0.00367342844f);
    p = fmaf(p, w, 0.00573950773f);
    p = fmaf(p, w, -0.0076224613f);
    p = fmaf(p, w, 0.00943887047f);
    p = fmaf(p, w, 1.00167406f);
    p = fmaf(p, w, 2.83297682f);
  }
  return p * x;
}

__device__ __forceinline__ float nrm_from_bits(uint32_t b) {
  const float lo = __uint_as_float(0xBF7FFFFFu);  // nextafterf(-1,0)
  float f = u01_from_bits(b);
  // f*2.0f is exact (pow2), so mul+add == fma bit-exactly; then lax.max(lo, .)
  float u = fmaxf(lo, f * 2.0f + lo);
  return 1.41421356237309515f * erfinv_xla(u);    // np.float32(np.sqrt(2))
}

__device__ __forceinline__ float sigmoidf_(float x) {
  return 1.0f / (1.0f + expf(-x));
}

// ---------------- Kernel A: encoder MLP -> per-(h,d) params + key ladder ----------------
// P layout (floats): [0:HD) base = prev_mean + M*alpha ; [HD:2HD) sigma*sqrt(dt) ;
// [2HD:3HD) nu ; [3HD:4HD) gamma ; [4HD:5HD) rate = lambda/M
// KEYS (uint32): [0,1]=k_diff  [2,3]=k_jmag  [4 .. 4+2*NSUB) = poisson subkeys
__global__ __launch_bounds__(256) void mjd_params(
    const float* __restrict__ x,
    const float* __restrict__ W0, const float* __restrict__ b0,
    const float* __restrict__ W1, const float* __restrict__ b1,
    const float* __restrict__ W2, const float* __restrict__ b2,
    const float* __restrict__ W3, const float* __restrict__ b3,
    const int* __restrict__ seedp, const int* __restrict__ mmp,
    float* __restrict__ P, uint32_t* __restrict__ KEYS) {
  const int d = blockIdx.x;      // one block per channel d
  const int t = threadIdx.x;
  __shared__ float xv[LSEQ];
  __shared__ float hA[WID], hB[WID];
  __shared__ float raw_s[P5];
  __shared__ float mu_s[NH], ma_s[NH];

  if (t < LSEQ) xv[t] = x[t * DCH + d];
  __syncthreads();
  {
    float acc = b0[t];
    const float* w = W0 + t * LSEQ;
    #pragma unroll 4
    for (int l = 0; l < LSEQ; ++l) acc = fmaf(xv[l], w[l], acc);
    hA[t] = fmaxf(acc, 0.0f);
  }
  __syncthreads();
  {
    float acc = b1[t];
    const float* w = W1 + t * WID;
    #pragma unroll 4
    for (int i = 0; i < WID; ++i) acc = fmaf(hA[i], w[i], acc);
    hB[t] = fmaxf(acc, 0.0f);
  }
  __syncthreads();
  {
    float acc = b2[t];
    const float* w = W2 + t * WID;
    #pragma unroll 4
    for (int i = 0; i < WID; ++i) acc = fmaf(hB[i], w[i], acc);
    hA[t] = fmaxf(acc, 0.0f);
  }
  __syncthreads();
  if (t < P5) {
    float acc = b3[t];
    const float* w = W3 + t * WID;
    #pragma unroll 4
    for (int i = 0; i < WID; ++i) acc = fmaf(hA[i], w[i], acc);
    raw_s[t] = acc;
  }
  __syncthreads();

  const int Mm = mmp[0];
  const float dtf = (float)(1.0 / (double)Mm);
  if (t < NH) {
    float mu  = raw_s[5 * t + 0];
    float sg  = sigmoidf_(raw_s[5 * t + 1]);
    float ll  = raw_s[5 * t + 2];
    float nuv = tanhf(raw_s[5 * t + 3]) * 0.5f;
    float gm  = sigmoidf_(raw_s[5 * t + 4]);
    float lamf = expf(fminf(ll, 0.0f));
    float km   = expf(nuv + 0.5f * gm * gm) - 1.0f;
    float a    = (mu - lamf * km - 0.5f * sg * sg) * dtf;
    float Ma   = (float)Mm * a;
    int hd = t * DCH + d;
    P[HD     + hd] = sg * sqrtf(dtf);
    P[2 * HD + hd] = nuv;
    P[3 * HD + hd] = gm;
    P[4 * HD + hd] = lamf / (float)Mm;
    mu_s[t] = mu;
    ma_s[t] = Ma;
  }
  __syncthreads();
  if (t == 0) {
    float prev = x[(LSEQ - 1) * DCH + d];   // s0[d]
    for (int h = 0; h < NH; ++h) {
      P[h * DCH + d] = prev + ma_s[h];      // prev_mean + M*alpha
      prev = prev + mu_s[h];                // cumsum of mu
    }
  }
  if (d == 0 && t == 0) {
    // key = jax.random.key(seed) -> (0, seed); fold-like split(key,3)
    uint32_t key0 = 0u, key1 = (uint32_t)seedp[0];
    uint32_t a, b;
    a = 0u; b = 0u; tf2x32(key0, key1, a, b); KEYS[0] = a; KEYS[1] = b;  // k_diff
    uint32_t kp0, kp1;
    a = 0u; b = 1u; tf2x32(key0, key1, a, b); kp0 = a; kp1 = b;          // k_pois
    a = 0u; b = 2u; tf2x32(key0, key1, a, b); KEYS[2] = a; KEYS[3] = b;  // k_jmag
    // knuth subkey ladder: subkey_t = tf(rng_t,(0,1)); rng_{t+1} = tf(rng_t,(0,0))
    uint32_t r0 = kp0, r1 = kp1;
    for (int tt = 0; tt < NSUB; ++tt) {
      a = 0u; b = 1u; tf2x32(r0, r1, a, b);
      KEYS[4 + 2 * tt] = a; KEYS[5 + 2 * tt] = b;
      a = 0u; b = 0u; tf2x32(r0, r1, a, b);
      r0 = a; r1 = b;
    }
  }
}

// ---------------- Kernel B: one thread per output element (n, h, d) ----------------
__global__ __launch_bounds__(256) void mjd_main(
    const float* __restrict__ P, const uint32_t* __restrict__ KEYS,
    const int* __restrict__ mmp, float* __restrict__ out, int total) {
  __shared__ uint32_t sk[4 + 2 * NSUB];
  if (threadIdx.x < 4 + 2 * NSUB) sk[threadIdx.x] = KEYS[threadIdx.x];
  __syncthreads();

  const int o = blockIdx.x * 256 + threadIdx.x;
  if (o >= total) return;
  const int Mm = mmp[0];
  const int d  = o & (DCH - 1);
  const int nh = o >> 6;            // n*NH + h
  const int h  = nh % NH;
  const int hd = h * DCH + d;

  const float base    = P[hd];
  const float ssd     = P[HD + hd];
  const float nuv     = P[2 * HD + hd];
  const float gm      = P[3 * HD + hd];
  const float rate    = P[4 * HD + hd];
  const float neg_lam = -rate;

  const uint32_t kd0 = sk[0], kd1 = sk[1], kj0 = sk[2], kj1 = sk[3];

  float sum_eps = 0.0f, nsum = 0.0f, jsum = 0.0f;
  // flat index into (K, NH, Mm, DCH): f = (nh*Mm + m)*DCH + d ; hi word = 0
  uint32_t f = (uint32_t)nh * (uint32_t)Mm * (uint32_t)DCH + (uint32_t)d;

  for (int m = 0; m < Mm; ++m, f += (uint32_t)DCH) {
    // eps_d ~ normal(k_diff)[f]
    sum_eps += nrm_from_bits(tf_bits32(kd0, kd1, 0u, f));

    // n_j ~ poisson(k_pois, rate)[f]  (Knuth; lam==0 -> 0)
    if (rate > 0.0f) {
      float lp = 0.0f;
      int k = 0;
      #pragma unroll 1
      for (int t = 0; t < NSUB; ++t) {
        if (!(lp > neg_lam)) break;
        ++k;
        uint32_t ub = tf_bits32(sk[4 + 2 * t], sk[5 + 2 * t], 0u, f);
        lp += logf(u01_from_bits(ub));
      }
      int nj = k - 1;
      if (nj > 0) {
        float njf = (float)nj;
        nsum += njf;
        // eps_j ~ normal(k_jmag)[f]; only needed when n_j > 0 (0*eps_j == 0 exactly)
        jsum += sqrtf(njf) * nrm_from_bits(tf_bits32(kj0, kj1, 0u, f));
      }
    }
  }

  out[o] = (base + ssd * sum_eps) + (nuv * nsum + gm * jsum);
}

extern "C" void kernel_launch(void* const* d_in, const int* in_sizes, int n_in,
                              void* d_out, int out_size, void* d_ws, size_t ws_size,
                              hipStream_t stream) {
  const float* x  = (const float*)d_in[0];
  const float* W0 = (const float*)d_in[1];
  const float* b0 = (const float*)d_in[2];
  const float* W1 = (const float*)d_in[3];
  const float* b1 = (const float*)d_in[4];
  const float* W2 = (const float*)d_in[5];
  const float* b2 = (const float*)d_in[6];
  const float* W3 = (const float*)d_in[7];
  const float* b3 = (const float*)d_in[8];
  const int* steps = (const int*)d_in[10];
  const int* seed  = (const int*)d_in[11];

  float* P = (float*)d_ws;
  uint32_t* KEYS = (uint32_t*)((char*)d_ws + 5 * HD * sizeof(float));

  mjd_params<<<DCH, 256, 0, stream>>>(x, W0, b0, W1, b1, W2, b2, W3, b3,
                                      seed, steps, P, KEYS);
  int grid = (out_size + 255) / 256;
  mjd_main<<<grid, 256, 0, stream>>>(P, KEYS, steps, (float*)d_out, out_size);
}

// Round 2
// 402.988 us; speedup vs baseline: 1.2275x; 1.2275x over previous
//
#include <hip/hip_runtime.h>
#include <cstdint>

// Problem constants (fixed shapes for this dataset)
#define LSEQ 96
#define DCH  64
#define WID  256
#define NH   24
#define P5   120    // NH*5
#define HD   1536   // NH*DCH
#define NSUB 12     // poisson subkey ladder depth; P(need > 12) ~ 1e-13

// ---------------- Threefry-2x32 (20 rounds), matches jax._src.prng ----------------
__device__ __forceinline__ uint32_t rotl32(uint32_t x, int r) {
  return (x << r) | (x >> (32 - r));
}

__device__ __forceinline__ void tf2x32(uint32_t k0, uint32_t k1,
                                       uint32_t& x0, uint32_t& x1) {
  uint32_t k2 = k0 ^ k1 ^ 0x1BD11BDAu;
  x0 += k0; x1 += k1;
#define TF_R(r) { x0 += x1; x1 = rotl32(x1, r); x1 ^= x0; }
  TF_R(13) TF_R(15) TF_R(26) TF_R(6)
  x0 += k1; x1 += k2 + 1u;
  TF_R(17) TF_R(29) TF_R(16) TF_R(24)
  x0 += k2; x1 += k0 + 2u;
  TF_R(13) TF_R(15) TF_R(26) TF_R(6)
  x0 += k0; x1 += k1 + 3u;
  TF_R(17) TF_R(29) TF_R(16) TF_R(24)
  x0 += k1; x1 += k2 + 4u;
  TF_R(13) TF_R(15) TF_R(26) TF_R(6)
  x0 += k2; x1 += k0 + 5u;
#undef TF_R
}

// partitionable 32-bit random bits at 64-bit counter (c0=hi, c1=lo): x0 ^ x1
__device__ __forceinline__ uint32_t tf_bits32(uint32_t k0, uint32_t k1,
                                              uint32_t c0, uint32_t c1) {
  tf2x32(k0, k1, c0, c1);
  return c0 ^ c1;
}

// ---------------- uniform / normal exactly as jax.random ----------------
__device__ __forceinline__ float u01_from_bits(uint32_t b) {
  return __uint_as_float((b >> 9) | 0x3f800000u) - 1.0f;  // k*2^-23, exact
}

// XLA ErfInv f32 (Giles 2010), as in xla/client/lib/math.cc
__device__ __forceinline__ float erfinv_xla(float x) {
  float w = -log1pf(-x * x);
  float p;
  if (w < 5.0f) {
    w = w - 2.5f;
    p = 2.81022636e-08f;
    p = fmaf(p, w, 3.43273939e-07f);
    p = fmaf(p, w, -3.5233877e-06f);
    p = fmaf(p, w, -4.39150654e-06f);
    p = fmaf(p, w, 0.00021858087f);
    p = fmaf(p, w, -0.00125372503f);
    p = fmaf(p, w, -0.00417768164f);
    p = fmaf(p, w, 0.246640727f);
    p = fmaf(p, w, 1.50140941f);
  } else {
    w = sqrtf(w) - 3.0f;
    p = -0.000200214257f;
    p = fmaf(p, w, 0.000100950558f);
    p = fmaf(p, w, 0.00134934322f);
    p = fmaf(p, w, -0.00367342844f);
    p = fmaf(p, w, 0.00573950773f);
    p = fmaf(p, w, -0.0076224613f);
    p = fmaf(p, w, 0.00943887047f);
    p = fmaf(p, w, 1.00167406f);
    p = fmaf(p, w, 2.83297682f);
  }
  return p * x;
}

__device__ __forceinline__ float nrm_from_bits(uint32_t b) {
  const float lo = __uint_as_float(0xBF7FFFFFu);  // nextafterf(-1,0)
  float f = u01_from_bits(b);
  float u = fmaxf(lo, f * 2.0f + lo);   // f*2 exact (pow2) -> mul+add == ref
  return 1.41421356237309515f * erfinv_xla(u);
}

__device__ __forceinline__ float sigmoidf_(float x) {
  return 1.0f / (1.0f + expf(-x));
}

// ---------------- Kernel A: encoder MLP -> per-(h,d) params + keys + thresholds --
// P layout (floats): [0:HD) base = prev_mean + M*alpha ; [HD:2HD) sigma*sqrt(dt) ;
// [2HD:3HD) nu ; [3HD:4HD) gamma ; [4HD:5HD) rate = lambda/M
// KEYS (uint32): [0,1]=k_diff  [2,3]=k_jmag  [4 .. 4+2*NSUB) = poisson subkeys
// KSTAR (uint32)[HD]: smallest k s.t. RN(logf(k*2^-23)) > -rate  (event iff bits>>9 >= k*)
__global__ __launch_bounds__(256) void mjd_params(
    const float* __restrict__ x,
    const float* __restrict__ W0, const float* __restrict__ b0,
    const float* __restrict__ W1, const float* __restrict__ b1,
    const float* __restrict__ W2, const float* __restrict__ b2,
    const float* __restrict__ W3, const float* __restrict__ b3,
    const int* __restrict__ seedp, const int* __restrict__ mmp,
    float* __restrict__ P, uint32_t* __restrict__ KEYS,
    uint32_t* __restrict__ KSTAR) {
  const int d = blockIdx.x;      // one block per channel d
  const int t = threadIdx.x;
  __shared__ float xv[LSEQ];
  __shared__ float hA[WID], hB[WID];
  __shared__ float raw_s[P5];
  __shared__ float mu_s[NH], ma_s[NH];

  if (t < LSEQ) xv[t] = x[t * DCH + d];
  __syncthreads();
  {
    float acc = b0[t];
    const float* w = W0 + t * LSEQ;
    #pragma unroll 4
    for (int l = 0; l < LSEQ; ++l) acc = fmaf(xv[l], w[l], acc);
    hA[t] = fmaxf(acc, 0.0f);
  }
  __syncthreads();
  {
    float acc = b1[t];
    const float* w = W1 + t * WID;
    #pragma unroll 4
    for (int i = 0; i < WID; ++i) acc = fmaf(hA[i], w[i], acc);
    hB[t] = fmaxf(acc, 0.0f);
  }
  __syncthreads();
  {
    float acc = b2[t];
    const float* w = W2 + t * WID;
    #pragma unroll 4
    for (int i = 0; i < WID; ++i) acc = fmaf(hB[i], w[i], acc);
    hA[t] = fmaxf(acc, 0.0f);
  }
  __syncthreads();
  if (t < P5) {
    float acc = b3[t];
    const float* w = W3 + t * WID;
    #pragma unroll 4
    for (int i = 0; i < WID; ++i) acc = fmaf(hA[i], w[i], acc);
    raw_s[t] = acc;
  }
  __syncthreads();

  const int Mm = mmp[0];
  const float dtf = (float)(1.0 / (double)Mm);
  if (t < NH) {
    float mu  = raw_s[5 * t + 0];
    float sg  = sigmoidf_(raw_s[5 * t + 1]);
    float ll  = raw_s[5 * t + 2];
    float nuv = tanhf(raw_s[5 * t + 3]) * 0.5f;
    float gm  = sigmoidf_(raw_s[5 * t + 4]);
    float lamf = expf(fminf(ll, 0.0f));
    float km   = expf(nuv + 0.5f * gm * gm) - 1.0f;
    float a    = (mu - lamf * km - 0.5f * sg * sg) * dtf;
    float Ma   = (float)Mm * a;
    int hd = t * DCH + d;
    float rate = lamf / (float)Mm;
    P[HD     + hd] = sg * sqrtf(dtf);
    P[2 * HD + hd] = nuv;
    P[3 * HD + hd] = gm;
    P[4 * HD + hd] = rate;
    mu_s[t] = mu;
    ma_s[t] = Ma;
    // exact integer threshold for the Knuth iter-1 event, same logf as mjd_main
    uint32_t ks;
    if (rate > 0.0f) {
      float neg_lam = -rate;
      uint32_t lo = 0u, hi = 1u << 23;   // lo: log(0)=-inf fails; hi: log(1)=0 passes
      while (hi - lo > 1u) {
        uint32_t mid = (lo + hi) >> 1;
        float u = (float)mid * 0x1p-23f;   // exact
        if (logf(u) > neg_lam) hi = mid; else lo = mid;
      }
      ks = hi;                             // event iff (bits>>9) >= ks
    } else {
      ks = 0x01000000u;                    // never fires
    }
    KSTAR[hd] = ks;
  }
  __syncthreads();
  if (t == 0) {
    // prev_mean[h] = s0 + cumsum(mu)[h-1], association matching the reference
    float s0 = x[(LSEQ - 1) * DCH + d];
    float c = 0.0f;
    P[d] = s0 + ma_s[0];
    for (int h = 1; h < NH; ++h) {
      c = c + mu_s[h - 1];                 // cumsum partial sums in ref order
      P[h * DCH + d] = (s0 + c) + ma_s[h];
    }
  }
  if (d == 0 && t == 0) {
    // key = jax.random.key(seed) -> (0, seed); fold-like split(key,3)
    uint32_t key0 = 0u, key1 = (uint32_t)seedp[0];
    uint32_t a, b;
    a = 0u; b = 0u; tf2x32(key0, key1, a, b); KEYS[0] = a; KEYS[1] = b;  // k_diff
    uint32_t kp0, kp1;
    a = 0u; b = 1u; tf2x32(key0, key1, a, b); kp0 = a; kp1 = b;          // k_pois
    a = 0u; b = 2u; tf2x32(key0, key1, a, b); KEYS[2] = a; KEYS[3] = b;  // k_jmag
    // knuth subkey ladder: subkey_t = tf(rng_t,(0,1)); rng_{t+1} = tf(rng_t,(0,0))
    uint32_t r0 = kp0, r1 = kp1;
    for (int tt = 0; tt < NSUB; ++tt) {
      a = 0u; b = 1u; tf2x32(r0, r1, a, b);
      KEYS[4 + 2 * tt] = a; KEYS[5 + 2 * tt] = b;
      a = 0u; b = 0u; tf2x32(r0, r1, a, b);
      r0 = a; r1 = b;
    }
  }
}

// ---------------- Kernel B: one thread per output element (n, h, d) ----------------
// Phase 1 (dense, branch-free): eps_d normal + integer event test -> bitmask.
// Phase 2 (compacted): full Knuth continuation + eps_j only for event (m)s.
__global__ __launch_bounds__(256) void mjd_main(
    const float* __restrict__ P, const uint32_t* __restrict__ KEYS,
    const uint32_t* __restrict__ KSTAR,
    const int* __restrict__ mmp, float* __restrict__ out, int total) {
  __shared__ uint32_t sk[4 + 2 * NSUB];
  if (threadIdx.x < 4 + 2 * NSUB) sk[threadIdx.x] = KEYS[threadIdx.x];
  __syncthreads();

  const int o = blockIdx.x * 256 + threadIdx.x;
  if (o >= total) return;
  const int Mm = mmp[0];
  const int d  = o & (DCH - 1);
  const int nh = o >> 6;            // n*NH + h
  const int h  = nh % NH;
  const int hd = h * DCH + d;

  const float base    = P[hd];
  const float ssd     = P[HD + hd];
  const float nuv     = P[2 * HD + hd];
  const float gm      = P[3 * HD + hd];
  const float rate    = P[4 * HD + hd];
  const float neg_lam = -rate;
  const uint32_t kstar = KSTAR[hd];

  const uint32_t kd0 = sk[0], kd1 = sk[1], kj0 = sk[2], kj1 = sk[3];
  const uint32_t sp0 = sk[4], sp1 = sk[5];   // poisson subkey t=0

  // flat index into (K, NH, Mm, DCH): f = (nh*Mm + m)*DCH + d ; hi word = 0
  const uint32_t f0 = (uint32_t)nh * (uint32_t)Mm * (uint32_t)DCH + (uint32_t)d;

  // ---- Phase 1: dense, no divergence ----
  float sum_eps = 0.0f;
  uint32_t ev = 0u;
  {
    uint32_t f = f0;
    for (int m = 0; m < Mm; ++m, f += (uint32_t)DCH) {
      sum_eps += nrm_from_bits(tf_bits32(kd0, kd1, 0u, f));
      uint32_t bu = tf_bits32(sp0, sp1, 0u, f);
      if ((bu >> 9) >= kstar) ev |= (1u << m);
    }
  }

  // ---- Phase 2: rare events only (ascending m preserves ref summation order) ----
  float nsum = 0.0f, jsum = 0.0f;
  while (ev) {
    int m = __builtin_ctz(ev);
    ev &= ev - 1u;
    uint32_t fm = f0 + (uint32_t)m * (uint32_t)DCH;
    float u0 = u01_from_bits(tf_bits32(sp0, sp1, 0u, fm));
    float lp = logf(u0);          // guaranteed > -lam by kstar construction
    int nj = 0;
    #pragma unroll 1
    for (int t = 1; t < NSUB; ++t) {
      if (!(lp > neg_lam)) break;
      ++nj;
      uint32_t ub = tf_bits32(sk[4 + 2 * t], sk[5 + 2 * t], 0u, fm);
      lp += logf(u01_from_bits(ub));
    }
    float njf = (float)nj;        // exact small-int float
    nsum += njf;
    float ej = nrm_from_bits(tf_bits32(kj0, kj1, 0u, fm));
    jsum += sqrtf(njf) * ej;
  }

  out[o] = (base + ssd * sum_eps) + (nuv * nsum + gm * jsum);
}

extern "C" void kernel_launch(void* const* d_in, const int* in_sizes, int n_in,
                              void* d_out, int out_size, void* d_ws, size_t ws_size,
                              hipStream_t stream) {
  const float* x  = (const float*)d_in[0];
  const float* W0 = (const float*)d_in[1];
  const float* b0 = (const float*)d_in[2];
  const float* W1 = (const float*)d_in[3];
  const float* b1 = (const float*)d_in[4];
  const float* W2 = (const float*)d_in[5];
  const float* b2 = (const float*)d_in[6];
  const float* W3 = (const float*)d_in[7];
  const float* b3 = (const float*)d_in[8];
  const int* steps = (const int*)d_in[10];
  const int* seed  = (const int*)d_in[11];

  float* P = (float*)d_ws;
  uint32_t* KEYS  = (uint32_t*)((char*)d_ws + 5 * HD * sizeof(float));
  uint32_t* KSTAR = KEYS + 64;

  mjd_params<<<DCH, 256, 0, stream>>>(x, W0, b0, W1, b1, W2, b2, W3, b3,
                                      seed, steps, P, KEYS, KSTAR);
  int grid = (out_size + 255) / 256;
  mjd_main<<<grid, 256, 0, stream>>>(P, KEYS, KSTAR, steps, (float*)d_out, out_size);
}

// Round 3
// 353.451 us; speedup vs baseline: 1.3995x; 1.1402x over previous
//
#include <hip/hip_runtime.h>
#include <cstdint>

// Problem constants (fixed shapes for this dataset)
#define LSEQ 96
#define DCH  64
#define WID  256
#define NH   24
#define P5   120    // NH*5
#define HD   1536   // NH*DCH
#define NSUB 12     // poisson subkey ladder depth; P(need > 12) ~ 1e-13

// ---------------- Threefry-2x32 (20 rounds), matches jax._src.prng ----------------
__device__ __forceinline__ uint32_t rotl32(uint32_t x, int r) {
  return (x << r) | (x >> (32 - r));
}

__device__ __forceinline__ void tf2x32(uint32_t k0, uint32_t k1,
                                       uint32_t& x0, uint32_t& x1) {
  uint32_t k2 = k0 ^ k1 ^ 0x1BD11BDAu;
  x0 += k0; x1 += k1;
#define TF_R(r) { x0 += x1; x1 = rotl32(x1, r); x1 ^= x0; }
  TF_R(13) TF_R(15) TF_R(26) TF_R(6)
  x0 += k1; x1 += k2 + 1u;
  TF_R(17) TF_R(29) TF_R(16) TF_R(24)
  x0 += k2; x1 += k0 + 2u;
  TF_R(13) TF_R(15) TF_R(26) TF_R(6)
  x0 += k0; x1 += k1 + 3u;
  TF_R(17) TF_R(29) TF_R(16) TF_R(24)
  x0 += k1; x1 += k2 + 4u;
  TF_R(13) TF_R(15) TF_R(26) TF_R(6)
  x0 += k2; x1 += k0 + 5u;
#undef TF_R
}

// partitionable 32-bit random bits at 64-bit counter (c0=hi, c1=lo): x0 ^ x1
__device__ __forceinline__ uint32_t tf_bits32(uint32_t k0, uint32_t k1,
                                              uint32_t c0, uint32_t c1) {
  tf2x32(k0, k1, c0, c1);
  return c0 ^ c1;
}

// ---------------- uniform / normal exactly as jax.random ----------------
__device__ __forceinline__ float u01_from_bits(uint32_t b) {
  return __uint_as_float((b >> 9) | 0x3f800000u) - 1.0f;  // k*2^-23, exact
}

// XLA ErfInv f32 (Giles 2010), as in xla/client/lib/math.cc
__device__ __forceinline__ float erfinv_xla(float x) {
  float w = -log1pf(-x * x);
  float p;
  if (w < 5.0f) {
    w = w - 2.5f;
    p = 2.81022636e-08f;
    p = fmaf(p, w, 3.43273939e-07f);
    p = fmaf(p, w, -3.5233877e-06f);
    p = fmaf(p, w, -4.39150654e-06f);
    p = fmaf(p, w, 0.00021858087f);
    p = fmaf(p, w, -0.00125372503f);
    p = fmaf(p, w, -0.00417768164f);
    p = fmaf(p, w, 0.246640727f);
    p = fmaf(p, w, 1.50140941f);
  } else {
    w = sqrtf(w) - 3.0f;
    p = -0.000200214257f;
    p = fmaf(p, w, 0.000100950558f);
    p = fmaf(p, w, 0.00134934322f);
    p = fmaf(p, w, -0.00367342844f);
    p = fmaf(p, w, 0.00573950773f);
    p = fmaf(p, w, -0.0076224613f);
    p = fmaf(p, w, 0.00943887047f);
    p = fmaf(p, w, 1.00167406f);
    p = fmaf(p, w, 2.83297682f);
  }
  return p * x;
}

__device__ __forceinline__ float nrm_from_bits(uint32_t b) {
  const float lo = __uint_as_float(0xBF7FFFFFu);  // nextafterf(-1,0)
  float f = u01_from_bits(b);
  float u = fmaxf(lo, f * 2.0f + lo);   // f*2 exact (pow2) -> mul+add == ref
  return 1.41421356237309515f * erfinv_xla(u);
}

__device__ __forceinline__ float sigmoidf_(float x) {
  return 1.0f / (1.0f + expf(-x));
}

// ---------------- Kernel A v2: encoder MLP, split-K x4, float4 loads -------------
// 1024 threads/block, one block per channel d. thread t: neuron n=t>>2, part p=t&3.
// P layout (floats): [0:HD) base = prev_mean + M*alpha ; [HD:2HD) sigma*sqrt(dt) ;
// [2HD:3HD) nu ; [3HD:4HD) gamma ; [4HD:5HD) rate = lambda/M
// KEYS (uint32): [0,1]=k_diff  [2,3]=k_jmag  [4 .. 4+2*NSUB) = poisson subkeys
// KSTAR (uint32)[HD]: smallest k s.t. RN(logf(k*2^-23)) > -rate (event iff bits>>9>=k*)
__global__ __launch_bounds__(1024) void mjd_params(
    const float* __restrict__ x,
    const float* __restrict__ W0, const float* __restrict__ b0,
    const float* __restrict__ W1, const float* __restrict__ b1,
    const float* __restrict__ W2, const float* __restrict__ b2,
    const float* __restrict__ W3, const float* __restrict__ b3,
    const int* __restrict__ seedp, const int* __restrict__ mmp,
    float* __restrict__ P, uint32_t* __restrict__ KEYS,
    uint32_t* __restrict__ KSTAR) {
  const int d = blockIdx.x;      // one block per channel d
  const int t = threadIdx.x;
  const int n = t >> 2;          // neuron 0..255
  const int p = t & 3;           // k-part 0..3
  __shared__ float xv[LSEQ];
  __shared__ float hA[WID], hB[WID];
  __shared__ float raw_s[P5];
  __shared__ float mu_s[NH], ma_s[NH];

  if (t < LSEQ) xv[t] = x[t * DCH + d];
  __syncthreads();

  // L0: 256x96 matvec, p covers 24 inputs (6 float4)
  {
    float acc = 0.0f;
    const float4* w4 = (const float4*)(W0 + n * LSEQ + p * 24);
    const float* xp = xv + p * 24;
    #pragma unroll
    for (int j = 0; j < 6; ++j) {
      float4 w = w4[j];
      acc = fmaf(xp[4 * j + 0], w.x, acc);
      acc = fmaf(xp[4 * j + 1], w.y, acc);
      acc = fmaf(xp[4 * j + 2], w.z, acc);
      acc = fmaf(xp[4 * j + 3], w.w, acc);
    }
    acc += __shfl_xor(acc, 1);
    acc += __shfl_xor(acc, 2);
    if (p == 0) hA[n] = fmaxf(acc + b0[n], 0.0f);
  }
  __syncthreads();

  // L1: 256x256, p covers 64 inputs (16 float4)
  {
    float acc = 0.0f;
    const float4* w4 = (const float4*)(W1 + n * WID + p * 64);
    const float* hp = hA + p * 64;
    #pragma unroll 4
    for (int j = 0; j < 16; ++j) {
      float4 w = w4[j];
      acc = fmaf(hp[4 * j + 0], w.x, acc);
      acc = fmaf(hp[4 * j + 1], w.y, acc);
      acc = fmaf(hp[4 * j + 2], w.z, acc);
      acc = fmaf(hp[4 * j + 3], w.w, acc);
    }
    acc += __shfl_xor(acc, 1);
    acc += __shfl_xor(acc, 2);
    if (p == 0) hB[n] = fmaxf(acc + b1[n], 0.0f);
  }
  __syncthreads();

  // L2: 256x256
  {
    float acc = 0.0f;
    const float4* w4 = (const float4*)(W2 + n * WID + p * 64);
    const float* hp = hB + p * 64;
    #pragma unroll 4
    for (int j = 0; j < 16; ++j) {
      float4 w = w4[j];
      acc = fmaf(hp[4 * j + 0], w.x, acc);
      acc = fmaf(hp[4 * j + 1], w.y, acc);
      acc = fmaf(hp[4 * j + 2], w.z, acc);
      acc = fmaf(hp[4 * j + 3], w.w, acc);
    }
    acc += __shfl_xor(acc, 1);
    acc += __shfl_xor(acc, 2);
    if (p == 0) hA[n] = fmaxf(acc + b2[n], 0.0f);
  }
  __syncthreads();

  // L3: 120x256
  if (n < P5) {
    float acc = 0.0f;
    const float4* w4 = (const float4*)(W3 + n * WID + p * 64);
    const float* hp = hA + p * 64;
    #pragma unroll 4
    for (int j = 0; j < 16; ++j) {
      float4 w = w4[j];
      acc = fmaf(hp[4 * j + 0], w.x, acc);
      acc = fmaf(hp[4 * j + 1], w.y, acc);
      acc = fmaf(hp[4 * j + 2], w.z, acc);
      acc = fmaf(hp[4 * j + 3], w.w, acc);
    }
    acc += __shfl_xor(acc, 1);
    acc += __shfl_xor(acc, 2);
    if (p == 0) raw_s[n] = acc + b3[n];
  }
  __syncthreads();

  const int Mm = mmp[0];
  const float dtf = (float)(1.0 / (double)Mm);
  if (t < NH) {
    float mu  = raw_s[5 * t + 0];
    float sg  = sigmoidf_(raw_s[5 * t + 1]);
    float ll  = raw_s[5 * t + 2];
    float nuv = tanhf(raw_s[5 * t + 3]) * 0.5f;
    float gm  = sigmoidf_(raw_s[5 * t + 4]);
    float lamf = expf(fminf(ll, 0.0f));
    float km   = expf(nuv + 0.5f * gm * gm) - 1.0f;
    float a    = (mu - lamf * km - 0.5f * sg * sg) * dtf;
    float Ma   = (float)Mm * a;
    int hd = t * DCH + d;
    float rate = lamf / (float)Mm;
    P[HD     + hd] = sg * sqrtf(dtf);
    P[2 * HD + hd] = nuv;
    P[3 * HD + hd] = gm;
    P[4 * HD + hd] = rate;
    mu_s[t] = mu;
    ma_s[t] = Ma;
    // exact integer threshold for the Knuth iter-1 event, same logf as mjd_main
    uint32_t ks;
    if (rate > 0.0f) {
      float neg_lam = -rate;
      uint32_t lo = 0u, hi = 1u << 23;   // lo: log(0)=-inf fails; hi: log(1)=0 passes
      while (hi - lo > 1u) {
        uint32_t mid = (lo + hi) >> 1;
        float u = (float)mid * 0x1p-23f;   // exact
        if (logf(u) > neg_lam) hi = mid; else lo = mid;
      }
      ks = hi;                             // event iff (bits>>9) >= ks
    } else {
      ks = 0x01000000u;                    // never fires
    }
    KSTAR[hd] = ks;
  }
  __syncthreads();
  if (t == 0) {
    // prev_mean[h] = s0 + cumsum(mu)[h-1], association matching the reference
    float s0 = x[(LSEQ - 1) * DCH + d];
    float c = 0.0f;
    P[d] = s0 + ma_s[0];
    for (int h = 1; h < NH; ++h) {
      c = c + mu_s[h - 1];                 // cumsum partial sums in ref order
      P[h * DCH + d] = (s0 + c) + ma_s[h];
    }
  }
  if (d == 0 && t == 0) {
    // key = jax.random.key(seed) -> (0, seed); fold-like split(key,3)
    uint32_t key0 = 0u, key1 = (uint32_t)seedp[0];
    uint32_t a, b;
    a = 0u; b = 0u; tf2x32(key0, key1, a, b); KEYS[0] = a; KEYS[1] = b;  // k_diff
    uint32_t kp0, kp1;
    a = 0u; b = 1u; tf2x32(key0, key1, a, b); kp0 = a; kp1 = b;          // k_pois
    a = 0u; b = 2u; tf2x32(key0, key1, a, b); KEYS[2] = a; KEYS[3] = b;  // k_jmag
    // knuth subkey ladder: subkey_t = tf(rng_t,(0,1)); rng_{t+1} = tf(rng_t,(0,0))
    uint32_t r0 = kp0, r1 = kp1;
    for (int tt = 0; tt < NSUB; ++tt) {
      a = 0u; b = 1u; tf2x32(r0, r1, a, b);
      KEYS[4 + 2 * tt] = a; KEYS[5 + 2 * tt] = b;
      a = 0u; b = 0u; tf2x32(r0, r1, a, b);
      r0 = a; r1 = b;
    }
  }
}

// ---------------- Kernel B: one thread per output element (n, h, d) ----------------
// Phase 1 (dense, branch-free, unrolled for Mm==20): eps_d normal + integer event
// test -> bitmask.  Phase 2 (compacted): full Knuth + eps_j only for event (m)s.
template <int MMC>
__device__ __forceinline__ void mjd_body(
    int Mm, int o,
    const float* __restrict__ P, const uint32_t* __restrict__ KSTAR,
    const uint32_t* sk, float* __restrict__ out) {
  const int M = MMC ? MMC : Mm;
  const int d  = o & (DCH - 1);
  const int nh = o >> 6;            // n*NH + h
  const int h  = nh % NH;
  const int hd = h * DCH + d;

  const float base    = P[hd];
  const float ssd     = P[HD + hd];
  const float nuv     = P[2 * HD + hd];
  const float gm      = P[3 * HD + hd];
  const float rate    = P[4 * HD + hd];
  const float neg_lam = -rate;
  const uint32_t kstar = KSTAR[hd];

  const uint32_t kd0 = sk[0], kd1 = sk[1], kj0 = sk[2], kj1 = sk[3];
  const uint32_t sp0 = sk[4], sp1 = sk[5];   // poisson subkey t=0

  // flat index into (K, NH, Mm, DCH): f = (nh*Mm + m)*DCH + d ; hi word = 0
  const uint32_t f0 = (uint32_t)nh * (uint32_t)M * (uint32_t)DCH + (uint32_t)d;

  // ---- Phase 1: dense, no divergence ----
  float sum_eps = 0.0f;
  uint32_t ev = 0u;
  {
    uint32_t f = f0;
    #pragma unroll
    for (int m = 0; m < M; ++m, f += (uint32_t)DCH) {
      sum_eps += nrm_from_bits(tf_bits32(kd0, kd1, 0u, f));
      uint32_t bu = tf_bits32(sp0, sp1, 0u, f);
      if ((bu >> 9) >= kstar) ev |= (1u << m);
    }
  }

  // ---- Phase 2: rare events only (ascending m preserves ref summation order) ----
  float nsum = 0.0f, jsum = 0.0f;
  while (ev) {
    int m = __builtin_ctz(ev);
    ev &= ev - 1u;
    uint32_t fm = f0 + (uint32_t)m * (uint32_t)DCH;
    float u0 = u01_from_bits(tf_bits32(sp0, sp1, 0u, fm));
    float lp = logf(u0);          // guaranteed > -lam by kstar construction
    int nj = 0;
    #pragma unroll 1
    for (int t = 1; t < NSUB; ++t) {
      if (!(lp > neg_lam)) break;
      ++nj;
      uint32_t ub = tf_bits32(sk[4 + 2 * t], sk[5 + 2 * t], 0u, fm);
      lp += logf(u01_from_bits(ub));
    }
    float njf = (float)nj;        // exact small-int float
    nsum += njf;
    float ej = nrm_from_bits(tf_bits32(kj0, kj1, 0u, fm));
    jsum += sqrtf(njf) * ej;
  }

  out[o] = (base + ssd * sum_eps) + (nuv * nsum + gm * jsum);
}

__global__ __launch_bounds__(256) void mjd_main(
    const float* __restrict__ P, const uint32_t* __restrict__ KEYS,
    const uint32_t* __restrict__ KSTAR,
    const int* __restrict__ mmp, float* __restrict__ out, int total) {
  __shared__ uint32_t sk[4 + 2 * NSUB];
  if (threadIdx.x < 4 + 2 * NSUB) sk[threadIdx.x] = KEYS[threadIdx.x];
  __syncthreads();

  const int o = blockIdx.x * 256 + threadIdx.x;
  if (o >= total) return;
  const int Mm = mmp[0];
  if (Mm == 20) {
    mjd_body<20>(Mm, o, P, KSTAR, sk, out);   // fully-unrolled phase 1
  } else {
    mjd_body<0>(Mm, o, P, KSTAR, sk, out);    // generic fallback
  }
}

extern "C" void kernel_launch(void* const* d_in, const int* in_sizes, int n_in,
                              void* d_out, int out_size, void* d_ws, size_t ws_size,
                              hipStream_t stream) {
  const float* x  = (const float*)d_in[0];
  const float* W0 = (const float*)d_in[1];
  const float* b0 = (const float*)d_in[2];
  const float* W1 = (const float*)d_in[3];
  const float* b1 = (const float*)d_in[4];
  const float* W2 = (const float*)d_in[5];
  const float* b2 = (const float*)d_in[6];
  const float* W3 = (const float*)d_in[7];
  const float* b3 = (const float*)d_in[8];
  const int* steps = (const int*)d_in[10];
  const int* seed  = (const int*)d_in[11];

  float* P = (float*)d_ws;
  uint32_t* KEYS  = (uint32_t*)((char*)d_ws + 5 * HD * sizeof(float));
  uint32_t* KSTAR = KEYS + 64;

  mjd_params<<<DCH, 1024, 0, stream>>>(x, W0, b0, W1, b1, W2, b2, W3, b3,
                                       seed, steps, P, KEYS, KSTAR);
  int grid = (out_size + 255) / 256;
  mjd_main<<<grid, 256, 0, stream>>>(P, KEYS, KSTAR, steps, (float*)d_out, out_size);
}

// Round 4
// 272.490 us; speedup vs baseline: 1.8153x; 1.2971x over previous
//
#include <hip/hip_runtime.h>
#include <cstdint>

// Problem constants (fixed shapes for this dataset)
#define LSEQ 96
#define DCH  64
#define WID  256
#define NH   24
#define P5   120    // NH*5
#define HD   1536   // NH*DCH
#define NSUB 12     // poisson subkey ladder depth; P(need > 12) ~ 1e-13

// ---------------- Threefry-2x32 (20 rounds), matches jax._src.prng ----------------
__device__ __forceinline__ uint32_t rotl32(uint32_t x, int r) {
  return (x << r) | (x >> (32 - r));
}

__device__ __forceinline__ void tf2x32(uint32_t k0, uint32_t k1,
                                       uint32_t& x0, uint32_t& x1) {
  uint32_t k2 = k0 ^ k1 ^ 0x1BD11BDAu;
  x0 += k0; x1 += k1;
#define TF_R(r) { x0 += x1; x1 = rotl32(x1, r); x1 ^= x0; }
  TF_R(13) TF_R(15) TF_R(26) TF_R(6)
  x0 += k1; x1 += k2 + 1u;
  TF_R(17) TF_R(29) TF_R(16) TF_R(24)
  x0 += k2; x1 += k0 + 2u;
  TF_R(13) TF_R(15) TF_R(26) TF_R(6)
  x0 += k0; x1 += k1 + 3u;
  TF_R(17) TF_R(29) TF_R(16) TF_R(24)
  x0 += k1; x1 += k2 + 4u;
  TF_R(13) TF_R(15) TF_R(26) TF_R(6)
  x0 += k2; x1 += k0 + 5u;
#undef TF_R
}

// Dual-counter threefry: same key, two independent (c0,c1) chains interleaved
// for explicit 2-way ILP (the round is a 3-inst serial dep chain per state).
__device__ __forceinline__ void tf2x32_dual(uint32_t k0, uint32_t k1,
                                            uint32_t& a0, uint32_t& a1,
                                            uint32_t& b0, uint32_t& b1) {
  uint32_t k2 = k0 ^ k1 ^ 0x1BD11BDAu;
  a0 += k0; a1 += k1; b0 += k0; b1 += k1;
#define TF_R2(r) { a0 += a1; b0 += b1; a1 = rotl32(a1, r); b1 = rotl32(b1, r); \
                   a1 ^= a0; b1 ^= b0; }
  TF_R2(13) TF_R2(15) TF_R2(26) TF_R2(6)
  a0 += k1; a1 += k2 + 1u; b0 += k1; b1 += k2 + 1u;
  TF_R2(17) TF_R2(29) TF_R2(16) TF_R2(24)
  a0 += k2; a1 += k0 + 2u; b0 += k2; b1 += k0 + 2u;
  TF_R2(13) TF_R2(15) TF_R2(26) TF_R2(6)
  a0 += k0; a1 += k1 + 3u; b0 += k0; b1 += k1 + 3u;
  TF_R2(17) TF_R2(29) TF_R2(16) TF_R2(24)
  a0 += k1; a1 += k2 + 4u; b0 += k1; b1 += k2 + 4u;
  TF_R2(13) TF_R2(15) TF_R2(26) TF_R2(6)
  a0 += k2; a1 += k0 + 5u; b0 += k2; b1 += k0 + 5u;
#undef TF_R2
}

// partitionable 32-bit random bits at 64-bit counter (c0=hi, c1=lo): x0 ^ x1
__device__ __forceinline__ uint32_t tf_bits32(uint32_t k0, uint32_t k1,
                                              uint32_t c0, uint32_t c1) {
  tf2x32(k0, k1, c0, c1);
  return c0 ^ c1;
}

// ---------------- uniform / normal exactly as jax.random ----------------
__device__ __forceinline__ float u01_from_bits(uint32_t b) {
  return __uint_as_float((b >> 9) | 0x3f800000u) - 1.0f;  // k*2^-23, exact
}

// XLA ErfInv f32 (Giles 2010). log1p(-x*x) -> __logf(fma(-x,x,1)): fma keeps the
// cancellation exact, v_log_f32 is ~1 ulp; downstream poly damps the diff (<1e-5
// in eps). The bit-critical comparisons (Knuth/kstar) do NOT go through this.
__device__ __forceinline__ float erfinv_fast(float x) {
  float w = -__logf(fmaf(-x, x, 1.0f));
  float p;
  if (w < 5.0f) {
    w = w - 2.5f;
    p = 2.81022636e-08f;
    p = fmaf(p, w, 3.43273939e-07f);
    p = fmaf(p, w, -3.5233877e-06f);
    p = fmaf(p, w, -4.39150654e-06f);
    p = fmaf(p, w, 0.00021858087f);
    p = fmaf(p, w, -0.00125372503f);
    p = fmaf(p, w, -0.00417768164f);
    p = fmaf(p, w, 0.246640727f);
    p = fmaf(p, w, 1.50140941f);
  } else {
    w = sqrtf(w) - 3.0f;
    p = -0.000200214257f;
    p = fmaf(p, w, 0.000100950558f);
    p = fmaf(p, w, 0.00134934322f);
    p = fmaf(p, w, -0.00367342844f);
    p = fmaf(p, w, 0.00573950773f);
    p = fmaf(p, w, -0.0076224613f);
    p = fmaf(p, w, 0.00943887047f);
    p = fmaf(p, w, 1.00167406f);
    p = fmaf(p, w, 2.83297682f);
  }
  return p * x;
}

__device__ __forceinline__ float nrm_from_u(float f) {
  const float lo = __uint_as_float(0xBF7FFFFFu);  // nextafterf(-1,0)
  float u = fmaxf(lo, f * 2.0f + lo);   // f*2 exact (pow2) -> mul+add == ref
  return 1.41421356237309515f * erfinv_fast(u);
}

__device__ __forceinline__ float sigmoidf_(float x) {
  return 1.0f / (1.0f + expf(-x));
}

// ---------------- Kernel A: encoder MLP, split-K x4, float4 loads -------------
__global__ __launch_bounds__(1024) void mjd_params(
    const float* __restrict__ x,
    const float* __restrict__ W0, const float* __restrict__ b0,
    const float* __restrict__ W1, const float* __restrict__ b1,
    const float* __restrict__ W2, const float* __restrict__ b2,
    const float* __restrict__ W3, const float* __restrict__ b3,
    const int* __restrict__ seedp, const int* __restrict__ mmp,
    float* __restrict__ P, uint32_t* __restrict__ KEYS,
    uint32_t* __restrict__ KSTAR) {
  const int d = blockIdx.x;      // one block per channel d
  const int t = threadIdx.x;
  const int n = t >> 2;          // neuron 0..255
  const int p = t & 3;           // k-part 0..3
  __shared__ float xv[LSEQ];
  __shared__ float hA[WID], hB[WID];
  __shared__ float raw_s[P5];
  __shared__ float mu_s[NH], ma_s[NH];

  if (t < LSEQ) xv[t] = x[t * DCH + d];
  __syncthreads();

  {
    float acc = 0.0f;
    const float4* w4 = (const float4*)(W0 + n * LSEQ + p * 24);
    const float* xp = xv + p * 24;
    #pragma unroll
    for (int j = 0; j < 6; ++j) {
      float4 w = w4[j];
      acc = fmaf(xp[4 * j + 0], w.x, acc);
      acc = fmaf(xp[4 * j + 1], w.y, acc);
      acc = fmaf(xp[4 * j + 2], w.z, acc);
      acc = fmaf(xp[4 * j + 3], w.w, acc);
    }
    acc += __shfl_xor(acc, 1);
    acc += __shfl_xor(acc, 2);
    if (p == 0) hA[n] = fmaxf(acc + b0[n], 0.0f);
  }
  __syncthreads();

  {
    float acc = 0.0f;
    const float4* w4 = (const float4*)(W1 + n * WID + p * 64);
    const float* hp = hA + p * 64;
    #pragma unroll 4
    for (int j = 0; j < 16; ++j) {
      float4 w = w4[j];
      acc = fmaf(hp[4 * j + 0], w.x, acc);
      acc = fmaf(hp[4 * j + 1], w.y, acc);
      acc = fmaf(hp[4 * j + 2], w.z, acc);
      acc = fmaf(hp[4 * j + 3], w.w, acc);
    }
    acc += __shfl_xor(acc, 1);
    acc += __shfl_xor(acc, 2);
    if (p == 0) hB[n] = fmaxf(acc + b1[n], 0.0f);
  }
  __syncthreads();

  {
    float acc = 0.0f;
    const float4* w4 = (const float4*)(W2 + n * WID + p * 64);
    const float* hp = hB + p * 64;
    #pragma unroll 4
    for (int j = 0; j < 16; ++j) {
      float4 w = w4[j];
      acc = fmaf(hp[4 * j + 0], w.x, acc);
      acc = fmaf(hp[4 * j + 1], w.y, acc);
      acc = fmaf(hp[4 * j + 2], w.z, acc);
      acc = fmaf(hp[4 * j + 3], w.w, acc);
    }
    acc += __shfl_xor(acc, 1);
    acc += __shfl_xor(acc, 2);
    if (p == 0) hA[n] = fmaxf(acc + b2[n], 0.0f);
  }
  __syncthreads();

  if (n < P5) {
    float acc = 0.0f;
    const float4* w4 = (const float4*)(W3 + n * WID + p * 64);
    const float* hp = hA + p * 64;
    #pragma unroll 4
    for (int j = 0; j < 16; ++j) {
      float4 w = w4[j];
      acc = fmaf(hp[4 * j + 0], w.x, acc);
      acc = fmaf(hp[4 * j + 1], w.y, acc);
      acc = fmaf(hp[4 * j + 2], w.z, acc);
      acc = fmaf(hp[4 * j + 3], w.w, acc);
    }
    acc += __shfl_xor(acc, 1);
    acc += __shfl_xor(acc, 2);
    if (p == 0) raw_s[n] = acc + b3[n];
  }
  __syncthreads();

  const int Mm = mmp[0];
  const float dtf = (float)(1.0 / (double)Mm);
  if (t < NH) {
    float mu  = raw_s[5 * t + 0];
    float sg  = sigmoidf_(raw_s[5 * t + 1]);
    float ll  = raw_s[5 * t + 2];
    float nuv = tanhf(raw_s[5 * t + 3]) * 0.5f;
    float gm  = sigmoidf_(raw_s[5 * t + 4]);
    float lamf = expf(fminf(ll, 0.0f));
    float km   = expf(nuv + 0.5f * gm * gm) - 1.0f;
    float a    = (mu - lamf * km - 0.5f * sg * sg) * dtf;
    float Ma   = (float)Mm * a;
    int hd = t * DCH + d;
    float rate = lamf / (float)Mm;
    P[HD     + hd] = sg * sqrtf(dtf);
    P[2 * HD + hd] = nuv;
    P[3 * HD + hd] = gm;
    P[4 * HD + hd] = rate;
    mu_s[t] = mu;
    ma_s[t] = Ma;
    // exact integer threshold for the Knuth iter-1 event, same precise logf as
    // the phase-2 Knuth loop in mjd_main
    uint32_t ks;
    if (rate > 0.0f) {
      float neg_lam = -rate;
      uint32_t lo = 0u, hi = 1u << 23;   // lo: log(0)=-inf fails; hi: log(1)=0 passes
      while (hi - lo > 1u) {
        uint32_t mid = (lo + hi) >> 1;
        float u = (float)mid * 0x1p-23f;   // exact
        if (logf(u) > neg_lam) hi = mid; else lo = mid;
      }
      ks = hi;                             // event iff (bits>>9) >= ks
    } else {
      ks = 0x01000000u;                    // never fires
    }
    KSTAR[hd] = ks;
  }
  __syncthreads();
  if (t == 0) {
    // prev_mean[h] = s0 + cumsum(mu)[h-1], association matching the reference
    float s0 = x[(LSEQ - 1) * DCH + d];
    float c = 0.0f;
    P[d] = s0 + ma_s[0];
    for (int h = 1; h < NH; ++h) {
      c = c + mu_s[h - 1];                 // cumsum partial sums in ref order
      P[h * DCH + d] = (s0 + c) + ma_s[h];
    }
  }
  if (d == 0 && t == 0) {
    // key = jax.random.key(seed) -> (0, seed); fold-like split(key,3)
    uint32_t key0 = 0u, key1 = (uint32_t)seedp[0];
    uint32_t a, b;
    a = 0u; b = 0u; tf2x32(key0, key1, a, b); KEYS[0] = a; KEYS[1] = b;  // k_diff
    uint32_t kp0, kp1;
    a = 0u; b = 1u; tf2x32(key0, key1, a, b); kp0 = a; kp1 = b;          // k_pois
    a = 0u; b = 2u; tf2x32(key0, key1, a, b); KEYS[2] = a; KEYS[3] = b;  // k_jmag
    uint32_t r0 = kp0, r1 = kp1;
    for (int tt = 0; tt < NSUB; ++tt) {
      a = 0u; b = 1u; tf2x32(r0, r1, a, b);
      KEYS[4 + 2 * tt] = a; KEYS[5 + 2 * tt] = b;
      a = 0u; b = 0u; tf2x32(r0, r1, a, b);
      r0 = a; r1 = b;
    }
  }
}

// ---- Phase 2 helper: Knuth continuation + jump magnitudes for event bits ----
// Precise logf here (bit-critical comparisons vs -lam), matching kstar's search.
__device__ __forceinline__ void poisson_events(
    uint32_t ev, uint32_t f0, float neg_lam,
    const uint32_t* sk, uint32_t kj0, uint32_t kj1,
    float& nsum, float& jsum) {
  const uint32_t sp0 = sk[4], sp1 = sk[5];
  while (ev) {
    int m = __builtin_ctz(ev);
    ev &= ev - 1u;
    uint32_t fm = f0 + (uint32_t)m * (uint32_t)DCH;
    float u0 = u01_from_bits(tf_bits32(sp0, sp1, 0u, fm));
    float lp = logf(u0);          // guaranteed > -lam by kstar construction
    int nj = 0;
    #pragma unroll 1
    for (int t = 1; t < NSUB; ++t) {
      if (!(lp > neg_lam)) break;
      ++nj;
      uint32_t ub = tf_bits32(sk[4 + 2 * t], sk[5 + 2 * t], 0u, fm);
      lp += logf(u01_from_bits(ub));
    }
    float njf = (float)nj;
    nsum += njf;
    uint32_t bj = tf_bits32(kj0, kj1, 0u, fm);
    jsum += sqrtf(njf) * nrm_from_u(u01_from_bits(bj));
  }
}

// ---------------- Kernel B: TWO output elements per thread ----------------
// Pairing (n, n + K/2): same (h,d) => shared params; 4 independent threefry
// chains per step for latency hiding (tf2x32_dual x2).
template <int MMC>
__device__ __forceinline__ void mjd_body2(
    int Mm, int o, int halfN,
    const float* __restrict__ P, const uint32_t* __restrict__ KSTAR,
    const uint32_t* sk, float* __restrict__ out) {
  const int M = MMC ? MMC : Mm;
  const int d  = o & (DCH - 1);
  const int nh = o >> 6;            // n*NH + h
  const int h  = nh % NH;
  const int hd = h * DCH + d;

  const float base    = P[hd];
  const float ssd     = P[HD + hd];
  const float nuv     = P[2 * HD + hd];
  const float gm      = P[3 * HD + hd];
  const float rate    = P[4 * HD + hd];
  const float neg_lam = -rate;
  const uint32_t kstar = KSTAR[hd];

  const uint32_t kd0 = sk[0], kd1 = sk[1], kj0 = sk[2], kj1 = sk[3];
  const uint32_t sp0 = sk[4], sp1 = sk[5];

  const int o2  = o + halfN;
  const int nh2 = o2 >> 6;          // same h, same d by construction
  const uint32_t fA = (uint32_t)nh  * (uint32_t)M * (uint32_t)DCH + (uint32_t)d;
  const uint32_t fB = (uint32_t)nh2 * (uint32_t)M * (uint32_t)DCH + (uint32_t)d;

  // ---- Phase 1: dense, branch-free, 4 independent tf chains ----
  float s1 = 0.0f, s2 = 0.0f;
  uint32_t ev1 = 0u, ev2 = 0u;
  {
    uint32_t f1 = fA, f2 = fB;
    #pragma unroll 4
    for (int m = 0; m < M; ++m, f1 += (uint32_t)DCH, f2 += (uint32_t)DCH) {
      uint32_t da0 = 0u, da1 = f1, db0 = 0u, db1 = f2;
      tf2x32_dual(kd0, kd1, da0, da1, db0, db1);
      uint32_t pa0 = 0u, pa1 = f1, pb0 = 0u, pb1 = f2;
      tf2x32_dual(sp0, sp1, pa0, pa1, pb0, pb1);
      s1 += nrm_from_u(u01_from_bits(da0 ^ da1));
      s2 += nrm_from_u(u01_from_bits(db0 ^ db1));
      if (((pa0 ^ pa1) >> 9) >= kstar) ev1 |= (1u << m);
      if (((pb0 ^ pb1) >> 9) >= kstar) ev2 |= (1u << m);
    }
  }

  // ---- Phase 2: rare events, ascending m per element (ref summation order) ----
  float n1 = 0.0f, j1 = 0.0f, n2 = 0.0f, j2 = 0.0f;
  poisson_events(ev1, fA, neg_lam, sk, kj0, kj1, n1, j1);
  poisson_events(ev2, fB, neg_lam, sk, kj0, kj1, n2, j2);

  out[o]  = (base + ssd * s1) + (nuv * n1 + gm * j1);
  out[o2] = (base + ssd * s2) + (nuv * n2 + gm * j2);
}

__global__ __launch_bounds__(256) void mjd_main2(
    const float* __restrict__ P, const uint32_t* __restrict__ KEYS,
    const uint32_t* __restrict__ KSTAR,
    const int* __restrict__ mmp, float* __restrict__ out, int halfN) {
  __shared__ uint32_t sk[4 + 2 * NSUB];
  if (threadIdx.x < 4 + 2 * NSUB) sk[threadIdx.x] = KEYS[threadIdx.x];
  __syncthreads();

  const int o = blockIdx.x * 256 + threadIdx.x;
  if (o >= halfN) return;
  const int Mm = mmp[0];
  if (Mm == 20) {
    mjd_body2<20>(Mm, o, halfN, P, KSTAR, sk, out);
  } else {
    mjd_body2<0>(Mm, o, halfN, P, KSTAR, sk, out);
  }
}

// ---- single-element fallback (only used if out_size isn't pair-aligned) ----
template <int MMC>
__device__ __forceinline__ void mjd_body1(
    int Mm, int o,
    const float* __restrict__ P, const uint32_t* __restrict__ KSTAR,
    const uint32_t* sk, float* __restrict__ out) {
  const int M = MMC ? MMC : Mm;
  const int d  = o & (DCH - 1);
  const int nh = o >> 6;
  const int h  = nh % NH;
  const int hd = h * DCH + d;
  const float base = P[hd], ssd = P[HD + hd], nuv = P[2 * HD + hd];
  const float gm = P[3 * HD + hd], rate = P[4 * HD + hd];
  const float neg_lam = -rate;
  const uint32_t kstar = KSTAR[hd];
  const uint32_t kd0 = sk[0], kd1 = sk[1], kj0 = sk[2], kj1 = sk[3];
  const uint32_t sp0 = sk[4], sp1 = sk[5];
  const uint32_t f0 = (uint32_t)nh * (uint32_t)M * (uint32_t)DCH + (uint32_t)d;
  float s1 = 0.0f; uint32_t ev = 0u;
  uint32_t f = f0;
  #pragma unroll 4
  for (int m = 0; m < M; ++m, f += (uint32_t)DCH) {
    s1 += nrm_from_u(u01_from_bits(tf_bits32(kd0, kd1, 0u, f)));
    if ((tf_bits32(sp0, sp1, 0u, f) >> 9) >= kstar) ev |= (1u << m);
  }
  float n1 = 0.0f, j1 = 0.0f;
  poisson_events(ev, f0, neg_lam, sk, kj0, kj1, n1, j1);
  out[o] = (base + ssd * s1) + (nuv * n1 + gm * j1);
}

__global__ __launch_bounds__(256) void mjd_main1(
    const float* __restrict__ P, const uint32_t* __restrict__ KEYS,
    const uint32_t* __restrict__ KSTAR,
    const int* __restrict__ mmp, float* __restrict__ out, int total) {
  __shared__ uint32_t sk[4 + 2 * NSUB];
  if (threadIdx.x < 4 + 2 * NSUB) sk[threadIdx.x] = KEYS[threadIdx.x];
  __syncthreads();
  const int o = blockIdx.x * 256 + threadIdx.x;
  if (o >= total) return;
  const int Mm = mmp[0];
  if (Mm == 20) mjd_body1<20>(Mm, o, P, KSTAR, sk, out);
  else          mjd_body1<0>(Mm, o, P, KSTAR, sk, out);
}

extern "C" void kernel_launch(void* const* d_in, const int* in_sizes, int n_in,
                              void* d_out, int out_size, void* d_ws, size_t ws_size,
                              hipStream_t stream) {
  const float* x  = (const float*)d_in[0];
  const float* W0 = (const float*)d_in[1];
  const float* b0 = (const float*)d_in[2];
  const float* W1 = (const float*)d_in[3];
  const float* b1 = (const float*)d_in[4];
  const float* W2 = (const float*)d_in[5];
  const float* b2 = (const float*)d_in[6];
  const float* W3 = (const float*)d_in[7];
  const float* b3 = (const float*)d_in[8];
  const int* steps = (const int*)d_in[10];
  const int* seed  = (const int*)d_in[11];

  float* P = (float*)d_ws;
  uint32_t* KEYS  = (uint32_t*)((char*)d_ws + 5 * HD * sizeof(float));
  uint32_t* KSTAR = KEYS + 64;

  mjd_params<<<DCH, 1024, 0, stream>>>(x, W0, b0, W1, b1, W2, b2, W3, b3,
                                       seed, steps, P, KEYS, KSTAR);
  // pair (n, n+K/2): valid iff out_size splits into two equal halves aligned
  // to whole (NH*DCH) sample-slabs
  if (out_size % (2 * NH * DCH) == 0) {
    int halfN = out_size / 2;
    int grid = (halfN + 255) / 256;
    mjd_main2<<<grid, 256, 0, stream>>>(P, KEYS, KSTAR, steps, (float*)d_out, halfN);
  } else {
    int grid = (out_size + 255) / 256;
    mjd_main1<<<grid, 256, 0, stream>>>(P, KEYS, KSTAR, steps, (float*)d_out, out_size);
  }
}